// Round 17
// baseline (60.611 us; speedup 1.0000x reference)
//
#include <hip/hip_runtime.h>
#include <stdint.h>
#include <math.h>

// ---------------------------------------------------------------------------
// SparseExplorerRouting, round 20.
//
// Carried facts (best = R19 52.4us; R1-R3/R5/R9-R19 PASSED absmax 0):
//   * jax_threefry_partitionable=True counter scheme; key(42) -> (0,42);
//     walk (v,w) = split child v*5+w; per-step children ctr (0,{0,1,2}).
//   * output int32 {flags[1024], sum_aborts, sum_restarts}.
//   * E-table argmax(E/w) trick, w=-log(u); minE<e^0.5 == min_sim<0.1.
//   * Pipe-rate/load-width models predict reliably; instruction-count
//     models for threefry were 4-8x off in the libm era.
//   * POST-R13 CALIBRATION: marginal paired-fold+HWlog cost ~250-350cy
//     (R13's 8->4 fold halving saved 2.1us over 5120 waves). Total w-work
//     = 20.5k folds ~ 2.5us device-wide at good occupancy -- the R8/R9
//     table failures were the 33us libm-f64 producer, not the table.
//   * R19 band (K-split, f32 dots, f32 outputs) 19.4us; R19 walk 33us.
//
// Round 20 change (w-production moved out of the walk, cheaply this time):
//   * band gains an rng TAIL: after the epilogue (no barrier changes, no
//     extra waves), each of the 4096 band waves produces W for ~1.25
//     walks via the EXACT R19 paired-prologue math (bit-identical f32
//     invw values) -> Wtab[walk][step][slot], 5.2 MB.
//   * walk_tab_kernel = R19 walk minus prologue; per-step per-lane f32
//     load Wtab[(wave*8+step)*32+sl_use]. Pick path bit-identical.
//     SALU key chain kept for rare cold paths.
//   * Tier-2 (ws too small): R19 pair verbatim (walk_pre). Tier-3 as ever.
// ---------------------------------------------------------------------------

#define HID        1024
#define NUM_WALKS  5
#define WALK_LEN   8
#define HALF_WIN   16
#define E_THRESH_F 1.6487213f           // exp(0.5) = exp(5 * BIRTH_DEATH_EPS)

#define CENTERS    16                   // centers per band block
#define SROWS      32                   // staged rows = CENTERS + 16 halo
#define KHALF      512                  // staged columns per pass

__device__ __forceinline__ void tf2x32(uint32_t k0, uint32_t k1,
                                       uint32_t& x0, uint32_t& x1) {
  uint32_t ks2 = k0 ^ k1 ^ 0x1BD11BDAu;
  x0 += k0; x1 += k1;
#define TFR(r) { x0 += x1; x1 = (x1 << (r)) | (x1 >> (32 - (r))); x1 ^= x0; }
  TFR(13) TFR(15) TFR(26) TFR(6)
  x0 += k1;  x1 += ks2 + 1u;
  TFR(17) TFR(29) TFR(16) TFR(24)
  x0 += ks2; x1 += k0 + 2u;
  TFR(13) TFR(15) TFR(26) TFR(6)
  x0 += k0;  x1 += k1 + 3u;
  TFR(17) TFR(29) TFR(16) TFR(24)
  x0 += k1;  x1 += ks2 + 4u;
  TFR(13) TFR(15) TFR(26) TFR(6)
  x0 += ks2; x1 += k0 + 5u;
#undef TFR
}

__device__ __forceinline__ uint32_t tf_fold(uint32_t k0, uint32_t k1,
                                            uint32_t c0, uint32_t c1) {
  tf2x32(k0, k1, c0, c1);
  return c0 ^ c1;
}

// w = -log(u), u = k*2^-23 (k = bits>>9), via HW v_log_f32.
// Proven safe on HW (R12-R19 absmax 0).
__device__ __forceinline__ double fast_neg_log(uint32_t bits) {
  const uint32_t k = bits >> 9;
  if (k == 0) return 87.33654475055310899;    // -log(2^-126) clamp
  const float u  = (float)k * 1.1920928955078125e-7f;   // k * 2^-23, exact
  const float l2 = __log2f(u);                          // v_log_f32
  return (double)l2 * -0.6931471805599453;
}

// Produce walk wk's 8 steps of invw (R19 paired-prologue math, verbatim
// values): lanes 0..31 = step 2t, lanes 32..63 = step 2t+1; slot sl ->
// candidate j = sl + (sl>15). One store per fold per lane.
__device__ __forceinline__ void produce_w(float* __restrict__ Wtab,
                                          int wk, int lane) {
  uint32_t k0 = 0u, k1 = (uint32_t)wk;
  tf2x32(0u, 42u, k0, k1);
  k0 = __builtin_amdgcn_readfirstlane(k0);
  k1 = __builtin_amdgcn_readfirstlane(k1);
  const int sl = lane & 31;
  const uint32_t jpk = (uint32_t)(sl + (sl > 15 ? 1 : 0));
#pragma unroll
  for (int t = 0; t < WALK_LEN / 2; ++t) {
    uint32_t ksA0 = 0u, ksA1 = 1u; tf2x32(k0, k1, ksA0, ksA1);
    uint32_t n0   = 0u, n1   = 0u; tf2x32(k0, k1, n0, n1);   // key 2t+1
    n0 = __builtin_amdgcn_readfirstlane(n0);
    n1 = __builtin_amdgcn_readfirstlane(n1);
    uint32_t ksB0 = 0u, ksB1 = 1u; tf2x32(n0, n1, ksB0, ksB1);
    uint32_t m0   = 0u, m1   = 0u; tf2x32(n0, n1, m0, m1);   // key 2t+2
    uint32_t sA0  = 0u, sA1  = 0u; tf2x32(ksA0, ksA1, sA0, sA1);  // at=0
    uint32_t sB0  = 0u, sB1  = 0u; tf2x32(ksB0, ksB1, sB0, sB1);  // at=0
    const uint32_t s0 = (lane & 32) ? sB0 : sA0;
    const uint32_t s1 = (lane & 32) ? sB1 : sA1;
    const uint32_t bits = tf_fold(s0, s1, 0u, jpk);
    const float invw = (float)(1.0 / fast_neg_log(bits));
    Wtab[(((size_t)wk * WALK_LEN + 2 * t + (lane >> 5)) << 5) + sl] = invw;
    k0 = __builtin_amdgcn_readfirstlane(m0);
    k1 = __builtin_amdgcn_readfirstlane(m1);
  }
}

// ---- fused band + rowsq + d_out zeroing + rng tail -------------------------
// Band body identical to R19 (proven); rng tail appended after epilogue.
__global__ __launch_bounds__(512) void band_fused_kernel(
    const float* __restrict__ H, float* __restrict__ sumsqf,
    float* __restrict__ Ef, float* __restrict__ Wtab, int nwalks,
    int* __restrict__ out, int out_n, int seq_len) {
  __shared__ __align__(16) float  tile[SROWS][KHALF];   // 64 KB
  __shared__ double ssq[SROWS];

  if (blockIdx.x == 0) {                 // fold d_out zeroing in (dispatch
    for (int t = threadIdx.x; t < out_n; t += 512) out[t] = 0;   // ordering
  }                                      // guarantees walk sees zeros)

  int wg = blockIdx.x;
  {
    const int nwg = gridDim.x;           // bijective XCD swizzle (nwg%8==0)
    if ((nwg & 7) == 0) wg = (wg & 7) * (nwg >> 3) + (wg >> 3);
  }
  const int wid  = (int)(threadIdx.x >> 6);   // 0..7
  const int lane = (int)(threadIdx.x & 63);
  const int i0   = wg * CENTERS;
  const float4* __restrict__ H4 = (const float4*)H;

  double acc[4]  = {0.0, 0.0, 0.0, 0.0};   // per staged row, across halves
  double dsum[2] = {0.0, 0.0};             // per-cc owner-lane band sums

#pragma unroll
  for (int half = 0; half < 2; ++half) {
    // ---- stage 4 rows per wave, cols [half*512, half*512+512) ----
#pragma unroll
    for (int rr = 0; rr < 4; ++rr) {
      const int local = wid * 4 + rr;    // wave-uniform
      const int row   = i0 + local;
      if (row < seq_len) {
        const float4* src = H4 + ((size_t)row << 8);
        float4* dst = (float4*)&tile[local][0];
#pragma unroll
        for (int kk = 0; kk < 2; ++kk) { // global chunk k = 2*half + kk
          float4 x = src[lane + ((half * 2 + kk) << 6)];
          dst[lane + (kk << 6)] = x;
          acc[rr] += (double)x.x * x.x + (double)x.y * x.y
                   + (double)x.z * x.z + (double)x.w * x.w;
        }
      }
    }
    if (half == 1) {                     // finalize sumsq: one butterfly
#pragma unroll
      for (int rr = 0; rr < 4; ++rr) {
        const int local = wid * 4 + rr;
        const int row   = i0 + local;
        if (row < seq_len) {
          double a = acc[rr];
#pragma unroll
          for (int off = 32; off; off >>= 1) a += __shfl_xor(a, off);
          if (lane == 0) {
            ssq[local] = a;
            if (local < CENTERS)
              sumsqf[row] = (float)a;    // == the (float) cast the walk's
          }                              //    cycle check used before
        }
      }
    }
    __syncthreads();

    // ---- 2 centers per wave, 16 partial dots each, from LDS half ----
#pragma unroll
    for (int cc = 0; cc < 2; ++cc) {
      const int cl = wid * 2 + cc;       // 0..15, wave-uniform
      const int i  = i0 + cl;
      if (i >= seq_len) continue;

      float a[8];                        // f32: no load-time cvt
      {
        const float4* rc = (const float4*)&tile[cl][0];
#pragma unroll
        for (int kk = 0; kk < 2; ++kk) {
          float4 x = rc[lane + (kk << 6)];
          a[4*kk+0] = x.x; a[4*kk+1] = x.y; a[4*kk+2] = x.z; a[4*kk+3] = x.w;
        }
      }

      // d-loop fully unrolled; per-lane 8-term f32 partial, one cvt.
      double p[16];
#pragma unroll
      for (int d = 1; d <= 16; ++d) {
        const float4* rb = (const float4*)&tile[cl + d][0];
        float ps = 0.0f;
#pragma unroll
        for (int kk = 0; kk < 2; ++kk) {
          float4 x = rb[lane + (kk << 6)];
          ps += a[4*kk+0] * x.x + a[4*kk+1] * x.y
              + a[4*kk+2] * x.z + a[4*kk+3] * x.w;
        }
        p[d-1] = (double)ps;
      }

      // multi-value reduce-scatter: value bit3..0 <- lane bit5..2 (f64)
#pragma unroll
      for (int v = 0; v < 8; ++v) {                     // stage xor 32
        double send = (lane & 32) ? p[v] : p[v+8];
        double recv = __shfl_xor(send, 32);
        double mine = (lane & 32) ? p[v+8] : p[v];
        p[v] = mine + recv;
      }
#pragma unroll
      for (int v = 0; v < 4; ++v) {                     // stage xor 16
        double send = (lane & 16) ? p[v] : p[v+4];
        double recv = __shfl_xor(send, 16);
        double mine = (lane & 16) ? p[v+4] : p[v];
        p[v] = mine + recv;
      }
#pragma unroll
      for (int v = 0; v < 2; ++v) {                     // stage xor 8
        double send = (lane & 8) ? p[v] : p[v+2];
        double recv = __shfl_xor(send, 8);
        double mine = (lane & 8) ? p[v+2] : p[v];
        p[v] = mine + recv;
      }
      {                                                 // stage xor 4
        double send = (lane & 4) ? p[0] : p[1];
        double recv = __shfl_xor(send, 4);
        double mine = (lane & 4) ? p[1] : p[0];
        p[0] = mine + recv;
      }
      p[0] += __shfl_xor(p[0], 2);                      // stage xor 2
      p[0] += __shfl_xor(p[0], 1);                      // stage xor 1

      dsum[cc] += p[0];                  // owner-lane: half-sum accumulate
    }
    __syncthreads();                     // compute done before re-stage
  }

  // ---- epilogue: lane owns d = v+1 for its cc centers; store f32 ----
  const int v = ((lane >> 2) & 1) | (((lane >> 3) & 1) << 1)
              | (((lane >> 4) & 1) << 2) | (((lane >> 5) & 1) << 3);
  const int d = v + 1;
#pragma unroll
  for (int cc = 0; cc < 2; ++cc) {
    const int cl = wid * 2 + cc;
    const int i  = i0 + cl;
    if (i < seq_len && (lane & 3) == 0 && i + d < seq_len) {
      const double ni = sqrt(ssq[cl]) + 1e-8;
      const double s  = dsum[cc] / (ni * (sqrt(ssq[cl + d]) + 1e-8));
      const float  Ev = (float)exp(5.0 * s);
      Ef[(size_t)i * 33 + 16 + d]       = Ev;
      Ef[(size_t)(i + d) * 33 + 16 - d] = Ev;
    }
  }

  // ---- rng tail: grid-wide waves produce Wtab (~1.25 walks each) ----
  if (Wtab != nullptr) {
    const int gw     = (int)blockIdx.x * 8 + wid;
    const int stride = (int)gridDim.x * 8;
    for (int wk = gw; wk < nwalks; wk += stride)
      produce_w(Wtab, wk, lane);
  }
}

// ---- per-row sum of squares (f64) + d_out zeroing (fallback tier only) -----
__global__ __launch_bounds__(256) void rowsq_kernel(
    const float* __restrict__ H, double* __restrict__ sumsq,
    int* __restrict__ out, int out_n, int seq_len) {
  if (blockIdx.x == 0) {
    for (int t = threadIdx.x; t < out_n; t += 256) out[t] = 0;
  }
  const int row  = (int)((blockIdx.x * blockDim.x + threadIdx.x) >> 6);
  const int lane = threadIdx.x & 63;
  if (row >= seq_len) return;
  const float4* r = (const float4*)(H + (size_t)row * HID);
  double acc = 0.0;
#pragma unroll
  for (int k = 0; k < 4; ++k) {
    float4 x = r[lane + (k << 6)];
    acc += (double)x.x * x.x + (double)x.y * x.y
         + (double)x.z * x.z + (double)x.w * x.w;
  }
#pragma unroll
  for (int off = 32; off; off >>= 1) acc += __shfl_xor(acc, off);
  if (lane == 0) sumsq[row] = acc;
}

// ---- walk kernel, TABLE variant: R19 body, invw loaded from Wtab -----------
__global__ __launch_bounds__(256) void walk_tab_kernel(
    const float* __restrict__ Ef, const float* __restrict__ sumsqf,
    const float* __restrict__ Wtab, const int* __restrict__ viol,
    int* __restrict__ out, int nv, int seq_len) {
  int wave = (int)((blockIdx.x * blockDim.x + threadIdx.x) >> 6);
  const int lane = threadIdx.x & 63;
  if (wave >= nv * NUM_WALKS) return;
  wave = __builtin_amdgcn_readfirstlane(wave);
  const int v     = wave / NUM_WALKS;
  const int start = viol[v];

  uint32_t key0 = 0u, key1 = (uint32_t)wave;
  tf2x32(0u, 42u, key0, key1);
  key0 = __builtin_amdgcn_readfirstlane(key0);
  key1 = __builtin_amdgcn_readfirstlane(key1);

  // ---- key chain (wave-uniform SALU, saved for cold paths) ----
  uint32_t k0s[WALK_LEN], k1s[WALK_LEN];
#pragma unroll
  for (int s = 0; s < WALK_LEN; ++s) {
    k0s[s] = key0; k1s[s] = key1;
    uint32_t nk0 = 0u, nk1 = 0u; tf2x32(key0, key1, nk0, nk1);
    key0 = __builtin_amdgcn_readfirstlane(nk0);
    key1 = __builtin_amdgcn_readfirstlane(nk1);
  }

  // consuming lane j reads slot sl = j - (j>16)
  const int sl_use = (lane < 33 && lane != HALF_WIN)
                   ? (lane - (lane > HALF_WIN)) : 0;
  const float* __restrict__ Wrow =
      Wtab + (((size_t)wave * WALK_LEN) << 5) + sl_use;

  int   cur = start, prev = start, plen = 1;
  float minE = 1e30f;
  bool  detected = false;
  int   aborts = 0, restarts = 0;
  // carried |h|^2 of prev / cur (stored f32 == the cast used before)
  float na_f = sumsqf[start], nb_f = na_f;

#pragma unroll
  for (int step = 0; step < WALK_LEN; ++step) {
    const int  myidx   = cur - HALF_WIN + lane;
    const bool myvalid = (lane < 33) && (lane != HALF_WIN) &&
                         (myidx >= 0) && (myidx < seq_len);
    const int  clipped = myidx < 0 ? 0 : (myidx >= seq_len ? seq_len - 1 : myidx);
    const float Ejf    = Ef[(size_t)cur * 33 + (lane < 33 ? lane : 0)];
    const float sq_win = sumsqf[clipped];   // window |h|^2 (f32), with Ejf
    const float invw_s = Wrow[(size_t)step << 5];   // bit-identical to R19

    bool found = false; int fails = 0, p = 0, cand = 0;
    float nc_f = 0.0f;
    for (int at = 0; at < 3; ++at) {
      float f; int bi;
      if (myvalid) {
        if (at == 0) {
          f = Ejf * invw_s;     // hot path: 1 f32 mul
        } else {                // cold path (rare): recompute from saved key
          uint32_t ks0 = 0u, ks1 = 1u; tf2x32(k0s[step], k1s[step], ks0, ks1);
          uint32_t s0 = 0u, s1 = (uint32_t)at; tf2x32(ks0, ks1, s0, s1);
          const uint32_t bits = tf_fold(s0, s1, 0u, (uint32_t)lane);
          f = (float)((double)Ejf / fast_neg_log(bits));
        }
        bi = lane;
      } else { f = -1.0f; bi = 1000; }
      // f32 argmax butterfly: b32 shuffles, f32 compares
#pragma unroll
      for (int off = 32; off; off >>= 1) {
        const float of = __shfl_xor(f, off);
        const int   oi = __shfl_xor(bi, off);
        if (of > f || (of == f && oi < bi)) { f = of; bi = oi; }
      }
      p    = bi;
      cand = cur - HALF_WIN + p;
      nc_f = __shfl(sq_win, p);     // == sumsqf[cand], b32 shuffle
      bool ok;
      if (plen < 2) ok = true;
      else {
        const float na = na_f, nb = nb_f, nc = nc_f;
        const float tr  = (na * nb * nc) /
                          ((na + 1e-8f) * (nb + 1e-8f) * (nc + 1e-8f));
        const float dev = fabsf(tr - rintf(tr));
        ok = (dev <= 0.1f) && (tr <= 1.5f);
      }
      if (ok) { found = true; break; }
      ++fails;
    }
    aborts += fails;

    if (found) {
      const float Ewin = __shfl(Ejf, p);   // f32 threshold path (proven R19)
      minE = fminf(minE, Ewin);
      const bool closed = (cand == start) && (plen > 2);
      prev = cur; cur = cand; plen += 1;
      na_f = nb_f; nb_f = nc_f;
      if (closed) { if (minE < E_THRESH_F) detected = true; break; }
    } else {
      ++restarts;                 // rare path: restart chain from saved key
      uint32_t kr0 = 0u, kr1 = 2u; tf2x32(k0s[step], k1s[step], kr0, kr1);
      uint32_t h0 = 0u, h1 = 0u; tf2x32(kr0, kr1, h0, h1);
      uint32_t l0 = 0u, l1 = 1u; tf2x32(kr0, kr1, l0, l1);
      const uint32_t hi = tf_fold(h0, h1, 0u, 0u);
      const uint32_t lo = tf_fold(l0, l1, 0u, 0u);
      const uint32_t span = (uint32_t)nv;
      uint32_t mult = (65536u % span); mult = (mult * mult) % span;
      const uint32_t r = ((hi % span) * mult + (lo % span)) % span;
      const int node = viol[r];
      cur = node; prev = node; plen = 1;
      na_f = sumsqf[node]; nb_f = na_f;
    }
  }

  if (lane == 0) {
    if (detected)      atomicOr(&out[v], 1);
    if (aborts != 0)   atomicAdd(&out[nv], aborts);
    if (restarts != 0) atomicAdd(&out[nv + 1], restarts);
  }
}

// ---- walk kernel, tier-2: R19 walk_pre VERBATIM (in-walk prologue) ---------
__global__ __launch_bounds__(256) void walk_pre_kernel(
    const float* __restrict__ Ef, const float* __restrict__ sumsqf,
    const int* __restrict__ viol, int* __restrict__ out,
    int nv, int seq_len) {
  int wave = (int)((blockIdx.x * blockDim.x + threadIdx.x) >> 6);
  const int lane = threadIdx.x & 63;
  if (wave >= nv * NUM_WALKS) return;
  wave = __builtin_amdgcn_readfirstlane(wave);
  const int v     = wave / NUM_WALKS;
  const int start = viol[v];

  uint32_t key0 = 0u, key1 = (uint32_t)wave;
  tf2x32(0u, 42u, key0, key1);
  key0 = __builtin_amdgcn_readfirstlane(key0);
  key1 = __builtin_amdgcn_readfirstlane(key1);

  uint32_t k0s[WALK_LEN], k1s[WALK_LEN];
#pragma unroll
  for (int s = 0; s < WALK_LEN; ++s) {
    k0s[s] = key0; k1s[s] = key1;
    uint32_t nk0 = 0u, nk1 = 0u; tf2x32(key0, key1, nk0, nk1);
    key0 = __builtin_amdgcn_readfirstlane(nk0);
    key1 = __builtin_amdgcn_readfirstlane(nk1);
  }

  const int  sl_mine = lane & 31;
  const uint32_t jpk = (uint32_t)(sl_mine + (sl_mine > 15 ? 1 : 0));
  float invwp[WALK_LEN / 2];
#pragma unroll
  for (int t = 0; t < WALK_LEN / 2; ++t) {
    uint32_t ksA0 = 0u, ksA1 = 1u; tf2x32(k0s[2*t],   k1s[2*t],   ksA0, ksA1);
    uint32_t sA0  = 0u, sA1  = 0u; tf2x32(ksA0, ksA1, sA0, sA1);   // at=0
    uint32_t ksB0 = 0u, ksB1 = 1u; tf2x32(k0s[2*t+1], k1s[2*t+1], ksB0, ksB1);
    uint32_t sB0  = 0u, sB1  = 0u; tf2x32(ksB0, ksB1, sB0, sB1);   // at=0
    const uint32_t s0 = (lane & 32) ? sB0 : sA0;   // 2-op per-lane select
    const uint32_t s1 = (lane & 32) ? sB1 : sA1;
    const uint32_t bits = tf_fold(s0, s1, 0u, jpk);
    invwp[t] = (float)(1.0 / fast_neg_log(bits));
  }

  const int sl_use = (lane < 33 && lane != HALF_WIN)
                   ? (lane - (lane > HALF_WIN)) : 0;

  int   cur = start, prev = start, plen = 1;
  float minE = 1e30f;
  bool  detected = false;
  int   aborts = 0, restarts = 0;
  float na_f = sumsqf[start], nb_f = na_f;

#pragma unroll
  for (int step = 0; step < WALK_LEN; ++step) {
    const int  myidx   = cur - HALF_WIN + lane;
    const bool myvalid = (lane < 33) && (lane != HALF_WIN) &&
                         (myidx >= 0) && (myidx < seq_len);
    const int  clipped = myidx < 0 ? 0 : (myidx >= seq_len ? seq_len - 1 : myidx);
    const float Ejf    = Ef[(size_t)cur * 33 + (lane < 33 ? lane : 0)];
    const float sq_win = sumsqf[clipped];
    const float invw_s = __shfl(invwp[step >> 1],
                                ((step & 1) << 5) + sl_use);

    bool found = false; int fails = 0, p = 0, cand = 0;
    float nc_f = 0.0f;
    for (int at = 0; at < 3; ++at) {
      float f; int bi;
      if (myvalid) {
        if (at == 0) {
          f = Ejf * invw_s;
        } else {
          uint32_t ks0 = 0u, ks1 = 1u; tf2x32(k0s[step], k1s[step], ks0, ks1);
          uint32_t s0 = 0u, s1 = (uint32_t)at; tf2x32(ks0, ks1, s0, s1);
          const uint32_t bits = tf_fold(s0, s1, 0u, (uint32_t)lane);
          f = (float)((double)Ejf / fast_neg_log(bits));
        }
        bi = lane;
      } else { f = -1.0f; bi = 1000; }
#pragma unroll
      for (int off = 32; off; off >>= 1) {
        const float of = __shfl_xor(f, off);
        const int   oi = __shfl_xor(bi, off);
        if (of > f || (of == f && oi < bi)) { f = of; bi = oi; }
      }
      p    = bi;
      cand = cur - HALF_WIN + p;
      nc_f = __shfl(sq_win, p);
      bool ok;
      if (plen < 2) ok = true;
      else {
        const float na = na_f, nb = nb_f, nc = nc_f;
        const float tr  = (na * nb * nc) /
                          ((na + 1e-8f) * (nb + 1e-8f) * (nc + 1e-8f));
        const float dev = fabsf(tr - rintf(tr));
        ok = (dev <= 0.1f) && (tr <= 1.5f);
      }
      if (ok) { found = true; break; }
      ++fails;
    }
    aborts += fails;

    if (found) {
      const float Ewin = __shfl(Ejf, p);
      minE = fminf(minE, Ewin);
      const bool closed = (cand == start) && (plen > 2);
      prev = cur; cur = cand; plen += 1;
      na_f = nb_f; nb_f = nc_f;
      if (closed) { if (minE < E_THRESH_F) detected = true; break; }
    } else {
      ++restarts;
      uint32_t kr0 = 0u, kr1 = 2u; tf2x32(k0s[step], k1s[step], kr0, kr1);
      uint32_t h0 = 0u, h1 = 0u; tf2x32(kr0, kr1, h0, h1);
      uint32_t l0 = 0u, l1 = 1u; tf2x32(kr0, kr1, l0, l1);
      const uint32_t hi = tf_fold(h0, h1, 0u, 0u);
      const uint32_t lo = tf_fold(l0, l1, 0u, 0u);
      const uint32_t span = (uint32_t)nv;
      uint32_t mult = (65536u % span); mult = (mult * mult) % span;
      const uint32_t r = ((hi % span) * mult + (lo % span)) % span;
      const int node = viol[r];
      cur = node; prev = node; plen = 1;
      na_f = sumsqf[node]; nb_f = na_f;
    }
  }

  if (lane == 0) {
    if (detected)      atomicOr(&out[v], 1);
    if (aborts != 0)   atomicAdd(&out[nv], aborts);
    if (restarts != 0) atomicAdd(&out[nv + 1], restarts);
  }
}

// ---- fallback: round-1 in-walk dot kernel (only if ws too small) -----------
__global__ __launch_bounds__(256) void walk_ref_kernel(
    const float* __restrict__ H, const int* __restrict__ viol,
    const double* __restrict__ sumsq, int* __restrict__ out,
    int nv, int seq_len) {
  const int wave = (int)((blockIdx.x * blockDim.x + threadIdx.x) >> 6);
  const int lane = threadIdx.x & 63;
  if (wave >= nv * NUM_WALKS) return;
  const int v     = wave / NUM_WALKS;
  const int start = viol[v];
  uint32_t key0 = 0u, key1 = (uint32_t)wave;
  tf2x32(0u, 42u, key0, key1);
  const float4* __restrict__ H4 = (const float4*)H;
  int    cur = start, prev = start, plen = 1;
  double min_sim = 1e9;
  bool   detected = false;
  int    aborts = 0, restarts = 0;
  for (int step = 0; step < WALK_LEN; ++step) {
    uint32_t nk0 = 0u, nk1 = 0u; tf2x32(key0, key1, nk0, nk1);
    uint32_t ks0 = 0u, ks1 = 1u; tf2x32(key0, key1, ks0, ks1);
    uint32_t kr0 = 0u, kr1 = 2u; tf2x32(key0, key1, kr0, kr1);
    const double ncur = sqrt(sumsq[cur]) + 1e-8;
    double a[16];
    {
      const float4* rc = H4 + ((size_t)cur << 8);
#pragma unroll
      for (int k = 0; k < 4; ++k) {
        float4 x = rc[lane + (k << 6)];
        a[4*k+0] = x.x; a[4*k+1] = x.y; a[4*k+2] = x.z; a[4*k+3] = x.w;
      }
    }
    double my_sim = 0.0;
    for (int jj = 0; jj < 33; ++jj) {
      const int idx = cur - HALF_WIN + jj;
      if (jj == HALF_WIN || idx < 0 || idx >= seq_len) continue;
      const float4* rb = H4 + ((size_t)idx << 8);
      double acc = 0.0;
#pragma unroll
      for (int k = 0; k < 4; ++k) {
        float4 x = rb[lane + (k << 6)];
        acc += a[4*k+0] * (double)x.x + a[4*k+1] * (double)x.y
             + a[4*k+2] * (double)x.z + a[4*k+3] * (double)x.w;
      }
#pragma unroll
      for (int off = 32; off; off >>= 1) acc += __shfl_xor(acc, off);
      const double s = acc / (ncur * (sqrt(sumsq[idx]) + 1e-8));
      if (lane == jj) my_sim = s;
    }
    bool found = false; int fails = 0, p = 0, cand = 0;
    const int  myidx   = cur - HALF_WIN + lane;
    const bool myvalid = (lane < 33) && (lane != HALF_WIN) &&
                         (myidx >= 0) && (myidx < seq_len);
    for (int at = 0; at < 3; ++at) {
      uint32_t s0 = 0u, s1 = (uint32_t)at; tf2x32(ks0, ks1, s0, s1);
      double z; int bi;
      if (myvalid) {
        const uint32_t bits = tf_fold(s0, s1, 0u, (uint32_t)lane);
        const uint32_t fb   = (bits >> 9) | 0x3f800000u;
        const float    f    = __uint_as_float(fb) - 1.0f;
        const float    u    = (f > 0.0f) ? f : 1.1754943508222875e-38f;
        const double   g    = -log(-log((double)u));
        z  = g + 5.0 * my_sim;
        bi = lane;
      } else { z = -1e300; bi = 1000; }
#pragma unroll
      for (int off = 32; off; off >>= 1) {
        const double oz = __shfl_xor(z, off);
        const int    oi = __shfl_xor(bi, off);
        if (oz > z || (oz == z && oi < bi)) { z = oz; bi = oi; }
      }
      p    = bi;
      cand = cur - HALF_WIN + p;
      bool ok;
      if (plen < 2) ok = true;
      else {
        const float na = (float)sumsq[prev], nb = (float)sumsq[cur],
                    nc = (float)sumsq[cand];
        const float tr  = (na * nb * nc) /
                          ((na + 1e-8f) * (nb + 1e-8f) * (nc + 1e-8f));
        const float dev = fabsf(tr - rintf(tr));
        ok = (dev <= 0.1f) && (tr <= 1.5f);
      }
      if (ok) { found = true; break; }
      ++fails;
    }
    aborts += fails;
    if (found) {
      const double sim = __shfl(my_sim, p);
      const double nm  = fmin(min_sim, sim);
      const bool closed = (cand == start) && (plen > 2);
      prev = cur; cur = cand; plen += 1; min_sim = nm;
      if (closed) { if (nm < 0.1) detected = true; break; }
    } else {
      ++restarts;
      uint32_t h0 = 0u, h1 = 0u; tf2x32(kr0, kr1, h0, h1);
      uint32_t l0 = 0u, l1 = 1u; tf2x32(kr0, kr1, l0, l1);
      const uint32_t hi = tf_fold(h0, h1, 0u, 0u);
      const uint32_t lo = tf_fold(l0, l1, 0u, 0u);
      const uint32_t span = (uint32_t)nv;
      uint32_t mult = (65536u % span); mult = (mult * mult) % span;
      const uint32_t r = ((hi % span) * mult + (lo % span)) % span;
      const int node = viol[r];
      cur = node; prev = node; plen = 1;
    }
    key0 = nk0; key1 = nk1;
  }
  if (lane == 0) {
    if (detected)      atomicOr(&out[v], 1);
    if (aborts != 0)   atomicAdd(&out[nv], aborts);
    if (restarts != 0) atomicAdd(&out[nv + 1], restarts);
  }
}

extern "C" void kernel_launch(void* const* d_in, const int* in_sizes, int n_in,
                              void* d_out, int out_size, void* d_ws, size_t ws_size,
                              hipStream_t stream) {
  const float* H    = (const float*)d_in[0];
  const int*   viol = (const int*)d_in[1];
  const int    nv      = in_sizes[1];
  const int    seq_len = in_sizes[0] / HID;
  const int    nwalks  = nv * NUM_WALKS;

  float* sumsqf = (float*)d_ws;                        // seq_len * 4 B
  float* Etabf  = (float*)((char*)d_ws + (size_t)seq_len * sizeof(float));
  const size_t need2 = (size_t)seq_len * sizeof(float)
                     + (size_t)seq_len * 33 * sizeof(float);
  float* Wtabf  = (float*)((char*)d_ws + ((need2 + 255) & ~(size_t)255));
  const size_t needW = ((need2 + 255) & ~(size_t)255)
                     + (size_t)nwalks * WALK_LEN * 32 * sizeof(float);

  const int wblocks = (nwalks + 3) / 4;

  if (ws_size >= needW) {
    const int blocks = (seq_len + CENTERS - 1) / CENTERS;   // 512 @ 8192
    band_fused_kernel<<<blocks, 512, 0, stream>>>(H, sumsqf, Etabf, Wtabf,
                                                  nwalks, (int*)d_out,
                                                  out_size, seq_len);
    walk_tab_kernel<<<wblocks, 256, 0, stream>>>(Etabf, sumsqf, Wtabf, viol,
                                                 (int*)d_out, nv, seq_len);
  } else if (ws_size >= need2) {
    const int blocks = (seq_len + CENTERS - 1) / CENTERS;
    band_fused_kernel<<<blocks, 512, 0, stream>>>(H, sumsqf, Etabf, nullptr,
                                                  nwalks, (int*)d_out,
                                                  out_size, seq_len);
    walk_pre_kernel<<<wblocks, 256, 0, stream>>>(Etabf, sumsqf, viol,
                                                 (int*)d_out, nv, seq_len);
  } else {
    double* sumsq = (double*)d_ws;                     // tier-3 scratch
    const int blocks = (seq_len + 3) / 4;
    rowsq_kernel<<<blocks, 256, 0, stream>>>(H, sumsq, (int*)d_out,
                                             out_size, seq_len);
    walk_ref_kernel<<<wblocks, 256, 0, stream>>>(H, viol, sumsq,
                                                 (int*)d_out, nv, seq_len);
  }
}

// Round 18
// 52.306 us; speedup vs baseline: 1.1588x; 1.1588x over previous
//
#include <hip/hip_runtime.h>
#include <stdint.h>
#include <math.h>

// ---------------------------------------------------------------------------
// SparseExplorerRouting, round 21.
//
// Carried facts (best = R19 52.4us; R1-R3/R5/R9-R20 PASSED absmax 0):
//   * jax_threefry_partitionable=True counter scheme; key(42) -> (0,42);
//     walk (v,w) = split child v*5+w; per-step children ctr (0,{0,1,2}).
//   * output int32 {flags[1024], sum_aborts, sum_restarts}.
//   * E-table argmax(E/w) trick, w=-log(u); minE<e^0.5 == min_sim<0.1.
//   * EMPIRICAL LAW (confirmed 6x: R5/R8/R9/R10/R11-R13/R20): bulk
//     w-production costs 25-33us in ANY dedicated producer (R20's band
//     tail: +29us); only in-walk overlap discounts it (~16us marginal).
//     Avenue permanently closed; R19's in-walk paired prologue is final.
//   * R19 config: band K-split + f32 dots + f32 outputs (19.4us); walk
//     R13-prologue + R18 f32 butterfly + R19 f32 tables (33us).
//   * Pipe-rate / load-width models predict reliably; everything else
//     (instruction counts, LDS-read cycles, occupancy levers) does not.
//
// Round 21 change (placement only; all values bit-identical to R19):
//   * E row stride padded 33 -> 64 floats (256 B, cache-line aligned).
//     Walk's per-step dependent load spans exactly 2 lines (was up to 3,
//     unaligned); row address becomes a shift. Band stores use the same
//     padded stride. Workspace ~2.1 MB.
// ---------------------------------------------------------------------------

#define HID        1024
#define NUM_WALKS  5
#define WALK_LEN   8
#define HALF_WIN   16
#define E_THRESH_F 1.6487213f           // exp(0.5) = exp(5 * BIRTH_DEATH_EPS)
#define ESTRIDE    64                   // padded E row stride (f32s)

#define CENTERS    16                   // centers per band block
#define SROWS      32                   // staged rows = CENTERS + 16 halo
#define KHALF      512                  // staged columns per pass

__device__ __forceinline__ void tf2x32(uint32_t k0, uint32_t k1,
                                       uint32_t& x0, uint32_t& x1) {
  uint32_t ks2 = k0 ^ k1 ^ 0x1BD11BDAu;
  x0 += k0; x1 += k1;
#define TFR(r) { x0 += x1; x1 = (x1 << (r)) | (x1 >> (32 - (r))); x1 ^= x0; }
  TFR(13) TFR(15) TFR(26) TFR(6)
  x0 += k1;  x1 += ks2 + 1u;
  TFR(17) TFR(29) TFR(16) TFR(24)
  x0 += ks2; x1 += k0 + 2u;
  TFR(13) TFR(15) TFR(26) TFR(6)
  x0 += k0;  x1 += k1 + 3u;
  TFR(17) TFR(29) TFR(16) TFR(24)
  x0 += k1;  x1 += ks2 + 4u;
  TFR(13) TFR(15) TFR(26) TFR(6)
  x0 += ks2; x1 += k0 + 5u;
#undef TFR
}

__device__ __forceinline__ uint32_t tf_fold(uint32_t k0, uint32_t k1,
                                            uint32_t c0, uint32_t c1) {
  tf2x32(k0, k1, c0, c1);
  return c0 ^ c1;
}

// w = -log(u), u = k*2^-23 (k = bits>>9), via HW v_log_f32.
// Proven safe on HW (R12-R20 absmax 0).
__device__ __forceinline__ double fast_neg_log(uint32_t bits) {
  const uint32_t k = bits >> 9;
  if (k == 0) return 87.33654475055310899;    // -log(2^-126) clamp
  const float u  = (float)k * 1.1920928955078125e-7f;   // k * 2^-23, exact
  const float l2 = __log2f(u);                          // v_log_f32
  return (double)l2 * -0.6931471805599453;
}

// ---- fused band + rowsq + d_out zeroing; K-split + f32 dots (R19 body) -----
__global__ __launch_bounds__(512) void band_fused_kernel(
    const float* __restrict__ H, float* __restrict__ sumsqf,
    float* __restrict__ Ef, int* __restrict__ out, int out_n, int seq_len) {
  __shared__ __align__(16) float  tile[SROWS][KHALF];   // 64 KB
  __shared__ double ssq[SROWS];

  if (blockIdx.x == 0) {                 // fold d_out zeroing in (dispatch
    for (int t = threadIdx.x; t < out_n; t += 512) out[t] = 0;   // ordering
  }                                      // guarantees walk sees zeros)

  int wg = blockIdx.x;
  {
    const int nwg = gridDim.x;           // bijective XCD swizzle (nwg%8==0)
    if ((nwg & 7) == 0) wg = (wg & 7) * (nwg >> 3) + (wg >> 3);
  }
  const int wid  = (int)(threadIdx.x >> 6);   // 0..7
  const int lane = (int)(threadIdx.x & 63);
  const int i0   = wg * CENTERS;
  const float4* __restrict__ H4 = (const float4*)H;

  double acc[4]  = {0.0, 0.0, 0.0, 0.0};   // per staged row, across halves
  double dsum[2] = {0.0, 0.0};             // per-cc owner-lane band sums

#pragma unroll
  for (int half = 0; half < 2; ++half) {
    // ---- stage 4 rows per wave, cols [half*512, half*512+512) ----
#pragma unroll
    for (int rr = 0; rr < 4; ++rr) {
      const int local = wid * 4 + rr;    // wave-uniform
      const int row   = i0 + local;
      if (row < seq_len) {
        const float4* src = H4 + ((size_t)row << 8);
        float4* dst = (float4*)&tile[local][0];
#pragma unroll
        for (int kk = 0; kk < 2; ++kk) { // global chunk k = 2*half + kk
          float4 x = src[lane + ((half * 2 + kk) << 6)];
          dst[lane + (kk << 6)] = x;
          acc[rr] += (double)x.x * x.x + (double)x.y * x.y
                   + (double)x.z * x.z + (double)x.w * x.w;
        }
      }
    }
    if (half == 1) {                     // finalize sumsq: one butterfly
#pragma unroll
      for (int rr = 0; rr < 4; ++rr) {
        const int local = wid * 4 + rr;
        const int row   = i0 + local;
        if (row < seq_len) {
          double a = acc[rr];
#pragma unroll
          for (int off = 32; off; off >>= 1) a += __shfl_xor(a, off);
          if (lane == 0) {
            ssq[local] = a;
            if (local < CENTERS)
              sumsqf[row] = (float)a;    // == the (float) cast the walk's
          }                              //    cycle check used before
        }
      }
    }
    __syncthreads();

    // ---- 2 centers per wave, 16 partial dots each, from LDS half ----
#pragma unroll
    for (int cc = 0; cc < 2; ++cc) {
      const int cl = wid * 2 + cc;       // 0..15, wave-uniform
      const int i  = i0 + cl;
      if (i >= seq_len) continue;

      float a[8];                        // f32: no load-time cvt
      {
        const float4* rc = (const float4*)&tile[cl][0];
#pragma unroll
        for (int kk = 0; kk < 2; ++kk) {
          float4 x = rc[lane + (kk << 6)];
          a[4*kk+0] = x.x; a[4*kk+1] = x.y; a[4*kk+2] = x.z; a[4*kk+3] = x.w;
        }
      }

      // d-loop fully unrolled; per-lane 8-term f32 partial, one cvt.
      double p[16];
#pragma unroll
      for (int d = 1; d <= 16; ++d) {
        const float4* rb = (const float4*)&tile[cl + d][0];
        float ps = 0.0f;
#pragma unroll
        for (int kk = 0; kk < 2; ++kk) {
          float4 x = rb[lane + (kk << 6)];
          ps += a[4*kk+0] * x.x + a[4*kk+1] * x.y
              + a[4*kk+2] * x.z + a[4*kk+3] * x.w;
        }
        p[d-1] = (double)ps;
      }

      // multi-value reduce-scatter: value bit3..0 <- lane bit5..2 (f64)
#pragma unroll
      for (int v = 0; v < 8; ++v) {                     // stage xor 32
        double send = (lane & 32) ? p[v] : p[v+8];
        double recv = __shfl_xor(send, 32);
        double mine = (lane & 32) ? p[v+8] : p[v];
        p[v] = mine + recv;
      }
#pragma unroll
      for (int v = 0; v < 4; ++v) {                     // stage xor 16
        double send = (lane & 16) ? p[v] : p[v+4];
        double recv = __shfl_xor(send, 16);
        double mine = (lane & 16) ? p[v+4] : p[v];
        p[v] = mine + recv;
      }
#pragma unroll
      for (int v = 0; v < 2; ++v) {                     // stage xor 8
        double send = (lane & 8) ? p[v] : p[v+2];
        double recv = __shfl_xor(send, 8);
        double mine = (lane & 8) ? p[v+2] : p[v];
        p[v] = mine + recv;
      }
      {                                                 // stage xor 4
        double send = (lane & 4) ? p[0] : p[1];
        double recv = __shfl_xor(send, 4);
        double mine = (lane & 4) ? p[1] : p[0];
        p[0] = mine + recv;
      }
      p[0] += __shfl_xor(p[0], 2);                      // stage xor 2
      p[0] += __shfl_xor(p[0], 1);                      // stage xor 1

      dsum[cc] += p[0];                  // owner-lane: half-sum accumulate
    }
    __syncthreads();                     // compute done before re-stage
  }

  // ---- epilogue: lane owns d = v+1 for its cc centers; store f32 ----
  const int v = ((lane >> 2) & 1) | (((lane >> 3) & 1) << 1)
              | (((lane >> 4) & 1) << 2) | (((lane >> 5) & 1) << 3);
  const int d = v + 1;
#pragma unroll
  for (int cc = 0; cc < 2; ++cc) {
    const int cl = wid * 2 + cc;
    const int i  = i0 + cl;
    if (i < seq_len && (lane & 3) == 0 && i + d < seq_len) {
      const double ni = sqrt(ssq[cl]) + 1e-8;
      const double s  = dsum[cc] / (ni * (sqrt(ssq[cl + d]) + 1e-8));
      const float  Ev = (float)exp(5.0 * s);
      Ef[((size_t)i << 6) + 16 + d]       = Ev;   // padded stride 64
      Ef[((size_t)(i + d) << 6) + 16 - d] = Ev;
    }
  }
}

// ---- per-row sum of squares (f64) + d_out zeroing (fallback tier only) -----
__global__ __launch_bounds__(256) void rowsq_kernel(
    const float* __restrict__ H, double* __restrict__ sumsq,
    int* __restrict__ out, int out_n, int seq_len) {
  if (blockIdx.x == 0) {
    for (int t = threadIdx.x; t < out_n; t += 256) out[t] = 0;
  }
  const int row  = (int)((blockIdx.x * blockDim.x + threadIdx.x) >> 6);
  const int lane = threadIdx.x & 63;
  if (row >= seq_len) return;
  const float4* r = (const float4*)(H + (size_t)row * HID);
  double acc = 0.0;
#pragma unroll
  for (int k = 0; k < 4; ++k) {
    float4 x = r[lane + (k << 6)];
    acc += (double)x.x * x.x + (double)x.y * x.y
         + (double)x.z * x.z + (double)x.w * x.w;
  }
#pragma unroll
  for (int off = 32; off; off >>= 1) acc += __shfl_xor(acc, off);
  if (lane == 0) sumsq[row] = acc;
}

// ---- walk kernel: R19 body verbatim; padded E stride -----------------------
__global__ __launch_bounds__(256) void walk_pre_kernel(
    const float* __restrict__ Ef, const float* __restrict__ sumsqf,
    const int* __restrict__ viol, int* __restrict__ out,
    int nv, int seq_len) {
  int wave = (int)((blockIdx.x * blockDim.x + threadIdx.x) >> 6);
  const int lane = threadIdx.x & 63;
  if (wave >= nv * NUM_WALKS) return;
  wave = __builtin_amdgcn_readfirstlane(wave);
  const int v     = wave / NUM_WALKS;
  const int start = viol[v];

  uint32_t key0 = 0u, key1 = (uint32_t)wave;
  tf2x32(0u, 42u, key0, key1);
  key0 = __builtin_amdgcn_readfirstlane(key0);
  key1 = __builtin_amdgcn_readfirstlane(key1);

  // ---- key chain (wave-uniform SALU, saved for cold paths) ----
  uint32_t k0s[WALK_LEN], k1s[WALK_LEN];
#pragma unroll
  for (int s = 0; s < WALK_LEN; ++s) {
    k0s[s] = key0; k1s[s] = key1;
    uint32_t nk0 = 0u, nk1 = 0u; tf2x32(key0, key1, nk0, nk1);
    key0 = __builtin_amdgcn_readfirstlane(nk0);
    key1 = __builtin_amdgcn_readfirstlane(nk1);
  }

  // ---- STEP-PAIRED prologue: 4 per-lane folds produce all 8 steps' w ----
  const int  sl_mine = lane & 31;
  const uint32_t jpk = (uint32_t)(sl_mine + (sl_mine > 15 ? 1 : 0));
  float invwp[WALK_LEN / 2];
#pragma unroll
  for (int t = 0; t < WALK_LEN / 2; ++t) {
    uint32_t ksA0 = 0u, ksA1 = 1u; tf2x32(k0s[2*t],   k1s[2*t],   ksA0, ksA1);
    uint32_t sA0  = 0u, sA1  = 0u; tf2x32(ksA0, ksA1, sA0, sA1);   // at=0
    uint32_t ksB0 = 0u, ksB1 = 1u; tf2x32(k0s[2*t+1], k1s[2*t+1], ksB0, ksB1);
    uint32_t sB0  = 0u, sB1  = 0u; tf2x32(ksB0, ksB1, sB0, sB1);   // at=0
    const uint32_t s0 = (lane & 32) ? sB0 : sA0;   // 2-op per-lane select
    const uint32_t s1 = (lane & 32) ? sB1 : sA1;
    const uint32_t bits = tf_fold(s0, s1, 0u, jpk);
    invwp[t] = (float)(1.0 / fast_neg_log(bits));
  }

  // consuming lane j reads slot sl = j - (j>16) from half (step&1)
  const int sl_use = (lane < 33 && lane != HALF_WIN)
                   ? (lane - (lane > HALF_WIN)) : 0;

  int   cur = start, prev = start, plen = 1;
  float minE = 1e30f;
  bool  detected = false;
  int   aborts = 0, restarts = 0;
  // carried |h|^2 of prev / cur (stored f32 == the cast used before)
  float na_f = sumsqf[start], nb_f = na_f;

#pragma unroll
  for (int step = 0; step < WALK_LEN; ++step) {
    const int  myidx   = cur - HALF_WIN + lane;
    const bool myvalid = (lane < 33) && (lane != HALF_WIN) &&
                         (myidx >= 0) && (myidx < seq_len);
    const int  clipped = myidx < 0 ? 0 : (myidx >= seq_len ? seq_len - 1 : myidx);
    const float Ejf    = Ef[((size_t)cur << 6) + (lane < 33 ? lane : 0)];
    const float sq_win = sumsqf[clipped];   // window |h|^2 (f32), with Ejf
    // my step's 1/w: one b32 bpermute from the paired prologue value
    const float invw_s = __shfl(invwp[step >> 1],
                                ((step & 1) << 5) + sl_use);

    bool found = false; int fails = 0, p = 0, cand = 0;
    float nc_f = 0.0f;
    for (int at = 0; at < 3; ++at) {
      float f; int bi;
      if (myvalid) {
        if (at == 0) {
          f = Ejf * invw_s;     // hot path: 1 f32 mul
        } else {                // cold path (rare): recompute from saved key
          uint32_t ks0 = 0u, ks1 = 1u; tf2x32(k0s[step], k1s[step], ks0, ks1);
          uint32_t s0 = 0u, s1 = (uint32_t)at; tf2x32(ks0, ks1, s0, s1);
          const uint32_t bits = tf_fold(s0, s1, 0u, (uint32_t)lane);
          f = (float)((double)Ejf / fast_neg_log(bits));
        }
        bi = lane;
      } else { f = -1.0f; bi = 1000; }
      // f32 argmax butterfly: b32 shuffles, f32 compares
#pragma unroll
      for (int off = 32; off; off >>= 1) {
        const float of = __shfl_xor(f, off);
        const int   oi = __shfl_xor(bi, off);
        if (of > f || (of == f && oi < bi)) { f = of; bi = oi; }
      }
      p    = bi;
      cand = cur - HALF_WIN + p;
      nc_f = __shfl(sq_win, p);     // == sumsqf[cand], b32 shuffle
      bool ok;
      if (plen < 2) ok = true;
      else {
        const float na = na_f, nb = nb_f, nc = nc_f;
        const float tr  = (na * nb * nc) /
                          ((na + 1e-8f) * (nb + 1e-8f) * (nc + 1e-8f));
        const float dev = fabsf(tr - rintf(tr));
        ok = (dev <= 0.1f) && (tr <= 1.5f);
      }
      if (ok) { found = true; break; }
      ++fails;
    }
    aborts += fails;

    if (found) {
      const float Ewin = __shfl(Ejf, p);   // f32 threshold path (proven R19)
      minE = fminf(minE, Ewin);
      const bool closed = (cand == start) && (plen > 2);
      prev = cur; cur = cand; plen += 1;
      na_f = nb_f; nb_f = nc_f;
      if (closed) { if (minE < E_THRESH_F) detected = true; break; }
    } else {
      ++restarts;                 // rare path: restart chain from saved key
      uint32_t kr0 = 0u, kr1 = 2u; tf2x32(k0s[step], k1s[step], kr0, kr1);
      uint32_t h0 = 0u, h1 = 0u; tf2x32(kr0, kr1, h0, h1);
      uint32_t l0 = 0u, l1 = 1u; tf2x32(kr0, kr1, l0, l1);
      const uint32_t hi = tf_fold(h0, h1, 0u, 0u);
      const uint32_t lo = tf_fold(l0, l1, 0u, 0u);
      const uint32_t span = (uint32_t)nv;
      uint32_t mult = (65536u % span); mult = (mult * mult) % span;
      const uint32_t r = ((hi % span) * mult + (lo % span)) % span;
      const int node = viol[r];
      cur = node; prev = node; plen = 1;
      na_f = sumsqf[node]; nb_f = na_f;
    }
  }

  if (lane == 0) {
    if (detected)      atomicOr(&out[v], 1);
    if (aborts != 0)   atomicAdd(&out[nv], aborts);
    if (restarts != 0) atomicAdd(&out[nv + 1], restarts);
  }
}

// ---- fallback: round-1 in-walk dot kernel (only if ws too small) -----------
__global__ __launch_bounds__(256) void walk_ref_kernel(
    const float* __restrict__ H, const int* __restrict__ viol,
    const double* __restrict__ sumsq, int* __restrict__ out,
    int nv, int seq_len) {
  const int wave = (int)((blockIdx.x * blockDim.x + threadIdx.x) >> 6);
  const int lane = threadIdx.x & 63;
  if (wave >= nv * NUM_WALKS) return;
  const int v     = wave / NUM_WALKS;
  const int start = viol[v];
  uint32_t key0 = 0u, key1 = (uint32_t)wave;
  tf2x32(0u, 42u, key0, key1);
  const float4* __restrict__ H4 = (const float4*)H;
  int    cur = start, prev = start, plen = 1;
  double min_sim = 1e9;
  bool   detected = false;
  int    aborts = 0, restarts = 0;
  for (int step = 0; step < WALK_LEN; ++step) {
    uint32_t nk0 = 0u, nk1 = 0u; tf2x32(key0, key1, nk0, nk1);
    uint32_t ks0 = 0u, ks1 = 1u; tf2x32(key0, key1, ks0, ks1);
    uint32_t kr0 = 0u, kr1 = 2u; tf2x32(key0, key1, kr0, kr1);
    const double ncur = sqrt(sumsq[cur]) + 1e-8;
    double a[16];
    {
      const float4* rc = H4 + ((size_t)cur << 8);
#pragma unroll
      for (int k = 0; k < 4; ++k) {
        float4 x = rc[lane + (k << 6)];
        a[4*k+0] = x.x; a[4*k+1] = x.y; a[4*k+2] = x.z; a[4*k+3] = x.w;
      }
    }
    double my_sim = 0.0;
    for (int jj = 0; jj < 33; ++jj) {
      const int idx = cur - HALF_WIN + jj;
      if (jj == HALF_WIN || idx < 0 || idx >= seq_len) continue;
      const float4* rb = H4 + ((size_t)idx << 8);
      double acc = 0.0;
#pragma unroll
      for (int k = 0; k < 4; ++k) {
        float4 x = rb[lane + (k << 6)];
        acc += a[4*k+0] * (double)x.x + a[4*k+1] * (double)x.y
             + a[4*k+2] * (double)x.z + a[4*k+3] * (double)x.w;
      }
#pragma unroll
      for (int off = 32; off; off >>= 1) acc += __shfl_xor(acc, off);
      const double s = acc / (ncur * (sqrt(sumsq[idx]) + 1e-8));
      if (lane == jj) my_sim = s;
    }
    bool found = false; int fails = 0, p = 0, cand = 0;
    const int  myidx   = cur - HALF_WIN + lane;
    const bool myvalid = (lane < 33) && (lane != HALF_WIN) &&
                         (myidx >= 0) && (myidx < seq_len);
    for (int at = 0; at < 3; ++at) {
      uint32_t s0 = 0u, s1 = (uint32_t)at; tf2x32(ks0, ks1, s0, s1);
      double z; int bi;
      if (myvalid) {
        const uint32_t bits = tf_fold(s0, s1, 0u, (uint32_t)lane);
        const uint32_t fb   = (bits >> 9) | 0x3f800000u;
        const float    f    = __uint_as_float(fb) - 1.0f;
        const float    u    = (f > 0.0f) ? f : 1.1754943508222875e-38f;
        const double   g    = -log(-log((double)u));
        z  = g + 5.0 * my_sim;
        bi = lane;
      } else { z = -1e300; bi = 1000; }
#pragma unroll
      for (int off = 32; off; off >>= 1) {
        const double oz = __shfl_xor(z, off);
        const int    oi = __shfl_xor(bi, off);
        if (oz > z || (oz == z && oi < bi)) { z = oz; bi = oi; }
      }
      p    = bi;
      cand = cur - HALF_WIN + p;
      bool ok;
      if (plen < 2) ok = true;
      else {
        const float na = (float)sumsq[prev], nb = (float)sumsq[cur],
                    nc = (float)sumsq[cand];
        const float tr  = (na * nb * nc) /
                          ((na + 1e-8f) * (nb + 1e-8f) * (nc + 1e-8f));
        const float dev = fabsf(tr - rintf(tr));
        ok = (dev <= 0.1f) && (tr <= 1.5f);
      }
      if (ok) { found = true; break; }
      ++fails;
    }
    aborts += fails;
    if (found) {
      const double sim = __shfl(my_sim, p);
      const double nm  = fmin(min_sim, sim);
      const bool closed = (cand == start) && (plen > 2);
      prev = cur; cur = cand; plen += 1; min_sim = nm;
      if (closed) { if (nm < 0.1) detected = true; break; }
    } else {
      ++restarts;
      uint32_t h0 = 0u, h1 = 0u; tf2x32(kr0, kr1, h0, h1);
      uint32_t l0 = 0u, l1 = 1u; tf2x32(kr0, kr1, l0, l1);
      const uint32_t hi = tf_fold(h0, h1, 0u, 0u);
      const uint32_t lo = tf_fold(l0, l1, 0u, 0u);
      const uint32_t span = (uint32_t)nv;
      uint32_t mult = (65536u % span); mult = (mult * mult) % span;
      const uint32_t r = ((hi % span) * mult + (lo % span)) % span;
      const int node = viol[r];
      cur = node; prev = node; plen = 1;
    }
    key0 = nk0; key1 = nk1;
  }
  if (lane == 0) {
    if (detected)      atomicOr(&out[v], 1);
    if (aborts != 0)   atomicAdd(&out[nv], aborts);
    if (restarts != 0) atomicAdd(&out[nv + 1], restarts);
  }
}

extern "C" void kernel_launch(void* const* d_in, const int* in_sizes, int n_in,
                              void* d_out, int out_size, void* d_ws, size_t ws_size,
                              hipStream_t stream) {
  const float* H    = (const float*)d_in[0];
  const int*   viol = (const int*)d_in[1];
  const int    nv      = in_sizes[1];
  const int    seq_len = in_sizes[0] / HID;
  const int    nwalks  = nv * NUM_WALKS;

  float* sumsqf = (float*)d_ws;                        // seq_len * 4 B
  float* Etabf  = (float*)((char*)d_ws + (size_t)seq_len * sizeof(float));
  const size_t need = (size_t)seq_len * sizeof(float)
                    + (size_t)seq_len * ESTRIDE * sizeof(float);

  const int wblocks = (nwalks + 3) / 4;

  if (ws_size >= need) {
    const int blocks = (seq_len + CENTERS - 1) / CENTERS;   // 512 @ 8192
    band_fused_kernel<<<blocks, 512, 0, stream>>>(H, sumsqf, Etabf,
                                                  (int*)d_out, out_size,
                                                  seq_len);
    walk_pre_kernel<<<wblocks, 256, 0, stream>>>(Etabf, sumsqf, viol,
                                                 (int*)d_out, nv, seq_len);
  } else {
    double* sumsq = (double*)d_ws;                     // tier-3 scratch
    const int blocks = (seq_len + 3) / 4;
    rowsq_kernel<<<blocks, 256, 0, stream>>>(H, sumsq, (int*)d_out,
                                             out_size, seq_len);
    walk_ref_kernel<<<wblocks, 256, 0, stream>>>(H, viol, sumsq,
                                                 (int*)d_out, nv, seq_len);
  }
}